// Round 1
// baseline (169.014 us; speedup 1.0000x reference)
//
#include <hip/hip_runtime.h>
#include <hip/hip_bf16.h>

#define N_TOTAL 8192
#define BROWS   4096
#define DDIM    256
#define NCLS    10
#define UPAD    12

typedef __attribute__((ext_vector_type(8))) short bf16x8;   // 8 bf16 (4 VGPRs)
typedef __attribute__((ext_vector_type(4))) float f32x4;

// ---- workspace layout (bytes) ----
static constexpr size_t OFF_X    = 0;                         // 8192*256*2 = 4 MiB
static constexpr size_t OFF_SQ   = 4u*1024u*1024u;            // 8192 f32
static constexpr size_t OFF_U    = OFF_SQ + 8192*4;           // 8192*12 f32
static constexpr size_t OFF_CP   = OFF_U  + 8192*UPAD*4;      // 64*256 f32 col partials
static constexpr size_t OFF_SC   = OFF_CP + 64*256*4;         // 32 f32 scalars
static constexpr size_t OFF_PART = OFF_SC + 32*4;             // 4096 f64 block partials

// scal layout: [0..4] -inv_bw? no: inv_bw (positive), [5] count_safe,
//              [6..15] a_scale[c], [16..25] b_scale[c]

// ---------------------------------------------------------------------------
// 1) convert rows to bf16, compute per-row squared norm of the *rounded* data
//    one wave per row; 2048 blocks x 256 threads
// ---------------------------------------------------------------------------
__global__ void k_prep(const float* __restrict__ src, const float* __restrict__ tgt,
                       unsigned short* __restrict__ X, float* __restrict__ sq) {
    int wid  = threadIdx.x >> 6;
    int lane = threadIdx.x & 63;
    int row  = blockIdx.x * 4 + wid;
    const float* p = (row < BROWS) ? (src + (size_t)row * DDIM)
                                   : (tgt + (size_t)(row - BROWS) * DDIM);
    f32x4 v = *reinterpret_cast<const f32x4*>(p + lane * 4);
    unsigned short h[4];
    float ssum = 0.f;
#pragma unroll
    for (int e = 0; e < 4; ++e) {
        unsigned bits = __float_as_uint(v[e]);
        unsigned r = (bits + 0x7FFFu + ((bits >> 16) & 1u)) >> 16;   // RNE to bf16
        h[e] = (unsigned short)r;
        float f = __uint_as_float(r << 16);
        ssum += f * f;
    }
    ushort4 us; us.x = h[0]; us.y = h[1]; us.z = h[2]; us.w = h[3];
    *reinterpret_cast<ushort4*>(X + (size_t)row * DDIM + lane * 4) = us;
#pragma unroll
    for (int off = 32; off > 0; off >>= 1) ssum += __shfl_xor(ssum, off);
    if (lane == 0) sq[row] = ssum;
}

// ---------------------------------------------------------------------------
// 2) per-dim column sums (64 row-chunks -> partials, fixed order later)
// ---------------------------------------------------------------------------
__global__ void k_colsum(const unsigned short* __restrict__ X, float* __restrict__ colpart) {
    int d  = threadIdx.x;          // 0..255 = dim
    int r0 = blockIdx.x * 128;     // 64 blocks
    float acc = 0.f;
    for (int r = 0; r < 128; ++r)
        acc += __uint_as_float((unsigned)X[(size_t)(r0 + r) * DDIM + d] << 16);
    colpart[blockIdx.x * DDIM + d] = acc;
}

// ---------------------------------------------------------------------------
// 3) stats: bandwidth (closed form), class sums, argmax presence, mask, count
//    single block, 256 threads, fixed-order reductions (deterministic)
// ---------------------------------------------------------------------------
__global__ void k_stats(const float* __restrict__ label, const float* __restrict__ logits,
                        const float* __restrict__ sq, const float* __restrict__ colpart,
                        float* __restrict__ scal) {
    __shared__ double dred[256];
    __shared__ float  cls[256][NCLS];
    __shared__ unsigned pm[256];
    __shared__ float  ssum[NCLS], tsum[NCLS];
    __shared__ unsigned presAll;
    int t = threadIdx.x;

    // sum over dims of (column sum)^2
    double cd = 0.0;
    for (int b = 0; b < 64; ++b) cd += (double)colpart[b * DDIM + t];
    dred[t] = cd * cd;
    __syncthreads();
    for (int s = 128; s > 0; s >>= 1) { if (t < s) dred[t] += dred[t + s]; __syncthreads(); }
    double S_cs = dred[0];
    __syncthreads();

    // sum of squared norms
    double ss = 0.0;
    for (int k = 0; k < 32; ++k) ss += (double)sq[t + 256 * k];
    dred[t] = ss;
    __syncthreads();
    for (int s = 128; s > 0; s >>= 1) { if (t < s) dred[t] += dred[t + s]; __syncthreads(); }
    double S_sq = dred[0];
    __syncthreads();

    // class partials over 4096 rows
    float sp[NCLS], tp[NCLS];
#pragma unroll
    for (int c = 0; c < NCLS; ++c) { sp[c] = 0.f; tp[c] = 0.f; }
    unsigned pres = 0;
    for (int k = 0; k < 16; ++k) {
        int r = t + 256 * k;
        const float* lr = label  + (size_t)r * NCLS;
        const float* gr = logits + (size_t)r * NCLS;
        float bv = -1e30f; int bc = 0;
#pragma unroll
        for (int c = 0; c < NCLS; ++c) {
            sp[c] += lr[c];
            float v = gr[c];
            tp[c] += v;
            if (v > bv) { bv = v; bc = c; }
        }
        pres |= (1u << bc);
    }
#pragma unroll
    for (int c = 0; c < NCLS; ++c) cls[t][c] = sp[c];
    pm[t] = pres;
    __syncthreads();
    if (t < NCLS) { float a = 0.f; for (int i = 0; i < 256; ++i) a += cls[i][t]; ssum[t] = a; }
    if (t == 0)  { unsigned p = 0; for (int i = 0; i < 256; ++i) p |= pm[i]; presAll = p; }
    __syncthreads();
#pragma unroll
    for (int c = 0; c < NCLS; ++c) cls[t][c] = tp[c];
    __syncthreads();
    if (t < NCLS) { float a = 0.f; for (int i = 0; i < 256; ++i) a += cls[i][t]; tsum[t] = a; }
    __syncthreads();

    if (t == 0) {
        double nf = (double)N_TOTAL;
        double sum_l2 = 2.0 * nf * S_sq - 2.0 * S_cs;
        if (sum_l2 < 0.0) sum_l2 = 0.0;
        double bw = sum_l2 / (nf * nf - nf) / 4.0;   // / kernel_mul^(kernel_num//2)
        for (int i = 0; i < 5; ++i) scal[i] = (float)(1.0 / (bw * (double)(1 << i)));
        int count = 0;
        for (int c = 0; c < NCLS; ++c) {
            float sv = ssum[c], tv = tsum[c];
            bool m = (sv > 0.f) && ((presAll >> c) & 1u);
            count += m ? 1 : 0;
            float sdiv = (sv == 0.f) ? 100.f : sv;
            float tdiv = (tv == 0.f) ? 100.f : tv;
            scal[6  + c] = m ? (1.f / sdiv) : 0.f;
            scal[16 + c] = m ? (1.f / tdiv) : 0.f;
        }
        scal[5] = (float)(count > 0 ? count : 1);
    }
}

// ---------------------------------------------------------------------------
// 4) build u (8192 x 12, padded): +label*a_scale for source, -logits*b_scale for target
// ---------------------------------------------------------------------------
__global__ void k_build_u(const float* __restrict__ label, const float* __restrict__ logits,
                          const float* __restrict__ scal, float* __restrict__ u) {
    int r = blockIdx.x * blockDim.x + threadIdx.x;
    if (r >= N_TOTAL) return;
    float* ur = u + (size_t)r * UPAD;
    if (r < BROWS) {
        const float* lr = label + (size_t)r * NCLS;
#pragma unroll
        for (int c = 0; c < NCLS; ++c) ur[c] = lr[c] * scal[6 + c];
    } else {
        const float* gr = logits + (size_t)(r - BROWS) * NCLS;
#pragma unroll
        for (int c = 0; c < NCLS; ++c) ur[c] = -gr[c] * scal[16 + c];
    }
    ur[10] = 0.f; ur[11] = 0.f;
}

// ---------------------------------------------------------------------------
// 5) main: upper-triangular 128x128 pair tiles; MFMA Gram + fused kernel/weight
//    grid (64,64), 256 threads = 4 waves of 64x64 quadrants
// ---------------------------------------------------------------------------
__global__ __launch_bounds__(256) void k_main(const unsigned short* __restrict__ X,
                                              const float* __restrict__ sq,
                                              const float* __restrict__ u,
                                              const float* __restrict__ scal,
                                              double* __restrict__ partials) {
    int bj = blockIdx.x, bi = blockIdx.y;
    int bid = bi * gridDim.x + bj;
    __shared__ float red[256];
    if (bj < bi) { if (threadIdx.x == 0) partials[bid] = 0.0; return; }

    int tid = threadIdx.x, lane = tid & 63, wid = tid >> 6;
    int wr = wid >> 1, wc = wid & 1;
    int i0 = bi * 128 + wr * 64;
    int j0 = bj * 128 + wc * 64;
    int lrow = lane & 15, kgrp = lane >> 4;

    float nib[5];
#pragma unroll
    for (int q = 0; q < 5; ++q) nib[q] = -scal[q];

    f32x4 acc[4][4];
#pragma unroll
    for (int a = 0; a < 4; ++a)
#pragma unroll
        for (int b = 0; b < 4; ++b) acc[a][b] = (f32x4){0.f, 0.f, 0.f, 0.f};

    const unsigned short* Ab = X + (size_t)(i0 + lrow) * DDIM + kgrp * 8;
    const unsigned short* Bb = X + (size_t)(j0 + lrow) * DDIM + kgrp * 8;

#pragma unroll 2
    for (int k0 = 0; k0 < DDIM; k0 += 32) {
        bf16x8 af[4], bfr[4];
#pragma unroll
        for (int f = 0; f < 4; ++f)
            af[f] = *reinterpret_cast<const bf16x8*>(Ab + (size_t)f * 16 * DDIM + k0);
#pragma unroll
        for (int f = 0; f < 4; ++f)
            bfr[f] = *reinterpret_cast<const bf16x8*>(Bb + (size_t)f * 16 * DDIM + k0);
#pragma unroll
        for (int a = 0; a < 4; ++a)
#pragma unroll
            for (int b = 0; b < 4; ++b)
                acc[a][b] = __builtin_amdgcn_mfma_f32_16x16x32_bf16(af[a], bfr[b], acc[a][b], 0, 0, 0);
    }

    // epilogue: per-pair l2 -> 5 exps -> weight dot -> accumulate
    float sqj[4];
    f32x4 uj0[4], uj1[4], uj2[4];
#pragma unroll
    for (int fc = 0; fc < 4; ++fc) {
        int jc = j0 + fc * 16 + lrow;           // C col = lane&15
        sqj[fc] = sq[jc];
        const f32x4* up = reinterpret_cast<const f32x4*>(u + (size_t)jc * UPAD);
        uj0[fc] = up[0]; uj1[fc] = up[1]; uj2[fc] = up[2];
    }

    float lp = 0.f;
#pragma unroll
    for (int fr = 0; fr < 4; ++fr) {
        int ibase = i0 + fr * 16 + kgrp * 4;    // C row = (lane>>4)*4 + reg
        f32x4 sqi = *reinterpret_cast<const f32x4*>(sq + ibase);
#pragma unroll
        for (int r = 0; r < 4; ++r) {
            const f32x4* up = reinterpret_cast<const f32x4*>(u + (size_t)(ibase + r) * UPAD);
            f32x4 ui0 = up[0], ui1 = up[1], ui2 = up[2];
            float sqir = sqi[r];
#pragma unroll
            for (int fc = 0; fc < 4; ++fc) {
                f32x4 w4 = ui0 * uj0[fc] + ui1 * uj1[fc] + ui2 * uj2[fc];
                float w = (w4.x + w4.y) + (w4.z + w4.w);
                float g = acc[fr][fc][r];
                float l2 = fmaxf(sqir + sqj[fc] - 2.f * g, 0.f);
                float kk = __expf(l2 * nib[0]) + __expf(l2 * nib[1]) + __expf(l2 * nib[2])
                         + __expf(l2 * nib[3]) + __expf(l2 * nib[4]);
                lp = fmaf(w, kk, lp);
            }
        }
    }

    red[tid] = lp;
    __syncthreads();
    for (int s = 128; s > 0; s >>= 1) { if (tid < s) red[tid] += red[tid + s]; __syncthreads(); }
    if (tid == 0) partials[bid] = (double)red[0] * ((bi == bj) ? 1.0 : 2.0);
}

// ---------------------------------------------------------------------------
// 6) final fixed-order reduction of 4096 block partials, divide by count
// ---------------------------------------------------------------------------
__global__ void k_final(const double* __restrict__ partials, const float* __restrict__ scal,
                        float* __restrict__ out) {
    __shared__ double dred[256];
    int t = threadIdx.x;
    double s = 0.0;
    for (int k = 0; k < 16; ++k) s += partials[t + 256 * k];
    dred[t] = s;
    __syncthreads();
    for (int st = 128; st > 0; st >>= 1) { if (t < st) dred[t] += dred[t + st]; __syncthreads(); }
    if (t == 0) out[0] = (float)(dred[0] / (double)scal[5]);
}

extern "C" void kernel_launch(void* const* d_in, const int* in_sizes, int n_in,
                              void* d_out, int out_size, void* d_ws, size_t ws_size,
                              hipStream_t stream) {
    const float* src    = (const float*)d_in[0];
    const float* tgt    = (const float*)d_in[1];
    const float* label  = (const float*)d_in[2];
    const float* logits = (const float*)d_in[3];

    char* ws = (char*)d_ws;
    unsigned short* X  = (unsigned short*)(ws + OFF_X);
    float* sq          = (float*)(ws + OFF_SQ);
    float* u           = (float*)(ws + OFF_U);
    float* colpart     = (float*)(ws + OFF_CP);
    float* scal        = (float*)(ws + OFF_SC);
    double* partials   = (double*)(ws + OFF_PART);

    k_prep   <<<2048, 256, 0, stream>>>(src, tgt, X, sq);
    k_colsum <<<64,   256, 0, stream>>>(X, colpart);
    k_stats  <<<1,    256, 0, stream>>>(label, logits, sq, colpart, scal);
    k_build_u<<<32,   256, 0, stream>>>(label, logits, scal, u);
    dim3 g(64, 64);
    k_main   <<<g,    256, 0, stream>>>(X, sq, u, scal, partials);
    k_final  <<<1,    256, 0, stream>>>(partials, scal, (float*)d_out);
}

// Round 2
// 107.245 us; speedup vs baseline: 1.5760x; 1.5760x over previous
//
#include <hip/hip_runtime.h>
#include <hip/hip_bf16.h>

#define N_TOTAL 8192
#define BROWS   4096
#define DDIM    256
#define NCLS    10
#define NB      64          // 128-row tiles per side
#define NTRI    (NB*(NB+1)/2)   // 2080 upper-tri blocks

typedef __attribute__((ext_vector_type(8))) short bf16x8;   // 8 bf16 (4 VGPRs)
typedef __attribute__((ext_vector_type(4))) float f32x4;

// ---- workspace layout (bytes) ----
static constexpr size_t OFF_X    = 0;              // 8192*256*2 = 4 MiB bf16 data
static constexpr size_t OFF_SQ   = 0x400000;       // 8192 f32 row sq-norms (32 KB)
static constexpr size_t OFF_XU   = 0x408000;       // 8192*32 bf16 padded weights (512 KB)
static constexpr size_t OFF_CP   = 0x488000;       // 64*256 f32 col partials (64 KB)
static constexpr size_t OFF_CLS  = 0x498000;       // 32*20 f32 class partials
static constexpr size_t OFF_PRES = 0x499000;       // 32 u32 presence partials
static constexpr size_t OFF_SC   = 0x49A000;       // 32 f32 scalars
static constexpr size_t OFF_PART = 0x49B000;       // 2080 f64 block partials

// scal: [0] = -1/(16*bw)  [5] = count_safe  [6..15] a_scale[c]  [16..25] b_scale[c]

// ---------------------------------------------------------------------------
// 1) rows -> bf16 (RNE), per-row squared norm of the rounded data
// ---------------------------------------------------------------------------
__global__ void k_prep(const float* __restrict__ src, const float* __restrict__ tgt,
                       unsigned short* __restrict__ X, float* __restrict__ sq) {
    int wid  = threadIdx.x >> 6;
    int lane = threadIdx.x & 63;
    int row  = blockIdx.x * 4 + wid;
    const float* p = (row < BROWS) ? (src + (size_t)row * DDIM)
                                   : (tgt + (size_t)(row - BROWS) * DDIM);
    f32x4 v = *reinterpret_cast<const f32x4*>(p + lane * 4);
    unsigned short h[4];
    float ssum = 0.f;
#pragma unroll
    for (int e = 0; e < 4; ++e) {
        unsigned bits = __float_as_uint(v[e]);
        unsigned r = (bits + 0x7FFFu + ((bits >> 16) & 1u)) >> 16;   // RNE to bf16
        h[e] = (unsigned short)r;
        float f = __uint_as_float(r << 16);
        ssum += f * f;
    }
    ushort4 us; us.x = h[0]; us.y = h[1]; us.z = h[2]; us.w = h[3];
    *reinterpret_cast<ushort4*>(X + (size_t)row * DDIM + lane * 4) = us;
#pragma unroll
    for (int off = 32; off > 0; off >>= 1) ssum += __shfl_xor(ssum, off);
    if (lane == 0) sq[row] = ssum;
}

// ---------------------------------------------------------------------------
// 2) per-dim column sums (64 row-chunks)
// ---------------------------------------------------------------------------
__global__ void k_colsum(const unsigned short* __restrict__ X, float* __restrict__ colpart) {
    int d  = threadIdx.x;
    int r0 = blockIdx.x * 128;
    float acc = 0.f;
    for (int r = 0; r < 128; ++r)
        acc += __uint_as_float((unsigned)X[(size_t)(r0 + r) * DDIM + d] << 16);
    colpart[blockIdx.x * DDIM + d] = acc;
}

// ---------------------------------------------------------------------------
// 2b) class sums + argmax presence, 32 blocks x 128 rows
// ---------------------------------------------------------------------------
__global__ void k_cls(const float* __restrict__ label, const float* __restrict__ logits,
                      float* __restrict__ clspart, unsigned* __restrict__ prespart) {
    __shared__ float buf[256][NCLS];
    __shared__ unsigned pm[128];
    int t = threadIdx.x, b = blockIdx.x;
    int r = b * 128 + (t & 127);
    if (t < 128) {
        const float* lr = label + (size_t)r * NCLS;
#pragma unroll
        for (int c = 0; c < NCLS; ++c) buf[t][c] = lr[c];
    } else {
        const float* gr = logits + (size_t)r * NCLS;
        float bv = -1e30f; int bc = 0;
#pragma unroll
        for (int c = 0; c < NCLS; ++c) {
            float v = gr[c];
            buf[t][c] = v;
            if (v > bv) { bv = v; bc = c; }
        }
        pm[t - 128] = 1u << bc;
    }
    __syncthreads();
    if (t < NCLS) {
        float a = 0.f;
        for (int i = 0; i < 128; ++i) a += buf[i][t];
        clspart[b * 20 + t] = a;
    } else if (t < 2 * NCLS) {
        float a = 0.f;
        for (int i = 128; i < 256; ++i) a += buf[i][t - NCLS];
        clspart[b * 20 + t] = a;
    }
    if (t == 0) {
        unsigned p = 0;
        for (int i = 0; i < 128; ++i) p |= pm[i];
        prespart[b] = p;
    }
}

// ---------------------------------------------------------------------------
// 3) stats: closed-form bandwidth, masks, scales (single small block)
// ---------------------------------------------------------------------------
__global__ void k_stats(const float* __restrict__ sq, const float* __restrict__ colpart,
                        const float* __restrict__ clspart, const unsigned* __restrict__ prespart,
                        float* __restrict__ scal) {
    __shared__ double dred[256];
    __shared__ float  cfin[2 * NCLS];
    __shared__ unsigned presAll;
    int t = threadIdx.x;

    double cd = 0.0;
    for (int b = 0; b < 64; ++b) cd += (double)colpart[b * DDIM + t];
    dred[t] = cd * cd;
    __syncthreads();
    for (int s = 128; s > 0; s >>= 1) { if (t < s) dred[t] += dred[t + s]; __syncthreads(); }
    double S_cs = dred[0];
    __syncthreads();

    double ss = 0.0;
    for (int k = 0; k < 32; ++k) ss += (double)sq[t + 256 * k];
    dred[t] = ss;
    __syncthreads();
    for (int s = 128; s > 0; s >>= 1) { if (t < s) dred[t] += dred[t + s]; __syncthreads(); }
    double S_sq = dred[0];
    __syncthreads();

    if (t < 2 * NCLS) {
        float a = 0.f;
        for (int b = 0; b < 32; ++b) a += clspart[b * 20 + t];
        cfin[t] = a;
    }
    if (t == 0) {
        unsigned p = 0;
        for (int b = 0; b < 32; ++b) p |= prespart[b];
        presAll = p;
    }
    __syncthreads();

    if (t == 0) {
        double nf = (double)N_TOTAL;
        double sum_l2 = 2.0 * nf * S_sq - 2.0 * S_cs;
        if (sum_l2 < 0.0) sum_l2 = 0.0;
        double bw = sum_l2 / (nf * nf - nf) / 4.0;   // / kernel_mul^(kernel_num//2)
        scal[0] = (float)(-1.0 / (16.0 * bw));       // natural-log exponent scale for e^(1/16 step)
        int count = 0;
        for (int c = 0; c < NCLS; ++c) {
            float sv = cfin[c], tv = cfin[NCLS + c];
            bool m = (sv > 0.f) && ((presAll >> c) & 1u);
            count += m ? 1 : 0;
            float sdiv = (sv == 0.f) ? 100.f : sv;
            float tdiv = (tv == 0.f) ? 100.f : tv;
            scal[6  + c] = m ? (1.f / sdiv) : 0.f;
            scal[16 + c] = m ? (1.f / tdiv) : 0.f;
        }
        scal[5] = (float)(count > 0 ? count : 1);
    }
}

// ---------------------------------------------------------------------------
// 4) build XU: 8192 x 32 bf16 padded weight rows (+label*a for src, -logit*b for tgt)
// ---------------------------------------------------------------------------
__global__ void k_build_xu(const float* __restrict__ label, const float* __restrict__ logits,
                           const float* __restrict__ scal, unsigned short* __restrict__ XU) {
    int r = blockIdx.x * blockDim.x + threadIdx.x;
    if (r >= N_TOTAL) return;
    float v[NCLS];
    if (r < BROWS) {
        const float* lr = label + (size_t)r * NCLS;
#pragma unroll
        for (int c = 0; c < NCLS; ++c) v[c] = lr[c] * scal[6 + c];
    } else {
        const float* gr = logits + (size_t)(r - BROWS) * NCLS;
#pragma unroll
        for (int c = 0; c < NCLS; ++c) v[c] = -gr[c] * scal[16 + c];
    }
    unsigned packed[16];
#pragma unroll
    for (int w = 0; w < 16; ++w) {
        unsigned lo = 0, hi = 0;
        if (2 * w < NCLS) {
            unsigned bits = __float_as_uint(v[2 * w]);
            lo = (bits + 0x7FFFu + ((bits >> 16) & 1u)) >> 16;
        }
        if (2 * w + 1 < NCLS) {
            unsigned bits = __float_as_uint(v[2 * w + 1]);
            hi = (bits + 0x7FFFu + ((bits >> 16) & 1u)) >> 16;
        }
        packed[w] = lo | (hi << 16);
    }
    uint4* out = reinterpret_cast<uint4*>(XU + (size_t)r * 32);
#pragma unroll
    for (int q = 0; q < 4; ++q)
        out[q] = make_uint4(packed[4*q], packed[4*q+1], packed[4*q+2], packed[4*q+3]);
}

// ---------------------------------------------------------------------------
// 5) main: triangular 128x128 tiles; MFMA Gram + MFMA weights + 1-exp kernel sum
// ---------------------------------------------------------------------------
__global__ __launch_bounds__(256, 4) void k_main(const unsigned short* __restrict__ X,
                                                 const unsigned short* __restrict__ XU,
                                                 const float* __restrict__ sq,
                                                 const float* __restrict__ scal,
                                                 double* __restrict__ partials) {
    int bid = blockIdx.x;
    int bi = 0, rem = bid;
    while (rem >= NB - bi) { rem -= NB - bi; ++bi; }
    int bj = bi + rem;

    int tid = threadIdx.x, lane = tid & 63, wid = tid >> 6;
    int wr = wid >> 1, wc = wid & 1;
    int i0 = bi * 128 + wr * 64;
    int j0 = bj * 128 + wc * 64;
    int lrow = lane & 15, kgrp = lane >> 4;

    __shared__ float red[256];
    float nb = scal[0];

    f32x4 acc[4][4];
#pragma unroll
    for (int a = 0; a < 4; ++a)
#pragma unroll
        for (int b = 0; b < 4; ++b) acc[a][b] = (f32x4){0.f, 0.f, 0.f, 0.f};

    const unsigned short* Ab = X + (size_t)(i0 + lrow) * DDIM + kgrp * 8;
    const unsigned short* Bb = X + (size_t)(j0 + lrow) * DDIM + kgrp * 8;

#pragma unroll 2
    for (int k0 = 0; k0 < DDIM; k0 += 32) {
        bf16x8 af[4], bfr[4];
#pragma unroll
        for (int f = 0; f < 4; ++f)
            af[f] = *reinterpret_cast<const bf16x8*>(Ab + (size_t)f * 16 * DDIM + k0);
#pragma unroll
        for (int f = 0; f < 4; ++f)
            bfr[f] = *reinterpret_cast<const bf16x8*>(Bb + (size_t)f * 16 * DDIM + k0);
#pragma unroll
        for (int a = 0; a < 4; ++a)
#pragma unroll
            for (int b = 0; b < 4; ++b)
                acc[a][b] = __builtin_amdgcn_mfma_f32_16x16x32_bf16(af[a], bfr[b], acc[a][b], 0, 0, 0);
    }

    // weight fragments (A side), loaded once
    const unsigned short* AU = XU + (size_t)(i0 + lrow) * 32 + kgrp * 8;
    const unsigned short* BU = XU + (size_t)(j0 + lrow) * 32 + kgrp * 8;
    bf16x8 au[4];
#pragma unroll
    for (int f = 0; f < 4; ++f)
        au[f] = *reinterpret_cast<const bf16x8*>(AU + (size_t)f * 16 * 32);

    float lp = 0.f;
#pragma unroll
    for (int g = 0; g < 4; ++g) {
        bf16x8 bu = *reinterpret_cast<const bf16x8*>(BU + (size_t)g * 16 * 32);
        f32x4 wg[4];
#pragma unroll
        for (int f = 0; f < 4; ++f)
            wg[f] = __builtin_amdgcn_mfma_f32_16x16x32_bf16(au[f], bu, (f32x4){0.f,0.f,0.f,0.f}, 0, 0, 0);

        float sqj = sq[j0 + g * 16 + lrow];
#pragma unroll
        for (int f = 0; f < 4; ++f) {
            f32x4 sqi = *reinterpret_cast<const f32x4*>(sq + i0 + f * 16 + kgrp * 4);
#pragma unroll
            for (int r = 0; r < 4; ++r) {
                float l2 = fmaxf(sqi[r] + sqj - 2.f * acc[f][g][r], 0.f);
                float e1 = __expf(l2 * nb);          // exp(-l2/(16 bw))
                float e2 = e1 * e1;
                float e4 = e2 * e2;
                float e8 = e4 * e4;
                float e16 = e8 * e8;
                float ks = ((e1 + e2) + (e4 + e8)) + e16;
                lp = fmaf(wg[f][r], ks, lp);
            }
        }
    }

    red[tid] = lp;
    __syncthreads();
    for (int s = 128; s > 0; s >>= 1) { if (tid < s) red[tid] += red[tid + s]; __syncthreads(); }
    if (tid == 0) partials[bid] = (double)red[0] * ((bi == bj) ? 1.0 : 2.0);
}

// ---------------------------------------------------------------------------
// 6) final fixed-order reduction, divide by count
// ---------------------------------------------------------------------------
__global__ void k_final(const double* __restrict__ partials, const float* __restrict__ scal,
                        float* __restrict__ out) {
    __shared__ double dred[256];
    int t = threadIdx.x;
    double s = 0.0;
    for (int k = 0; k < 9; ++k) {
        int idx = t + 256 * k;
        if (idx < NTRI) s += partials[idx];
    }
    dred[t] = s;
    __syncthreads();
    for (int st = 128; st > 0; st >>= 1) { if (t < st) dred[t] += dred[t + st]; __syncthreads(); }
    if (t == 0) out[0] = (float)(dred[0] / (double)scal[5]);
}

extern "C" void kernel_launch(void* const* d_in, const int* in_sizes, int n_in,
                              void* d_out, int out_size, void* d_ws, size_t ws_size,
                              hipStream_t stream) {
    const float* src    = (const float*)d_in[0];
    const float* tgt    = (const float*)d_in[1];
    const float* label  = (const float*)d_in[2];
    const float* logits = (const float*)d_in[3];

    char* ws = (char*)d_ws;
    unsigned short* X   = (unsigned short*)(ws + OFF_X);
    float* sq           = (float*)(ws + OFF_SQ);
    unsigned short* XU  = (unsigned short*)(ws + OFF_XU);
    float* colpart      = (float*)(ws + OFF_CP);
    float* clspart      = (float*)(ws + OFF_CLS);
    unsigned* prespart  = (unsigned*)(ws + OFF_PRES);
    float* scal         = (float*)(ws + OFF_SC);
    double* partials    = (double*)(ws + OFF_PART);

    k_prep    <<<2048, 256, 0, stream>>>(src, tgt, X, sq);
    k_colsum  <<<64,   256, 0, stream>>>(X, colpart);
    k_cls     <<<32,   256, 0, stream>>>(label, logits, clspart, prespart);
    k_stats   <<<1,    256, 0, stream>>>(sq, colpart, clspart, prespart, scal);
    k_build_xu<<<32,   256, 0, stream>>>(label, logits, scal, XU);
    k_main    <<<NTRI, 256, 0, stream>>>(X, XU, sq, scal, partials);
    k_final   <<<1,    256, 0, stream>>>(partials, scal, (float*)d_out);
}

// Round 3
// 64.974 us; speedup vs baseline: 2.6013x; 1.6506x over previous
//
#include <hip/hip_runtime.h>
#include <hip/hip_bf16.h>

#define N_TOTAL 8192
#define BROWS   4096
#define DDIM    256
#define NCLS    10
#define NB      64              // 128-row tiles per side
#define NTRI    (NB*(NB+1)/2)   // 2080 upper-tri blocks (= 8*260)

typedef __attribute__((ext_vector_type(8))) short bf16x8;   // 8 bf16 (4 VGPRs)
typedef __attribute__((ext_vector_type(4))) float f32x4;
typedef __attribute__((ext_vector_type(8))) unsigned short u16x8;

// ---- workspace layout (bytes) ----
static constexpr size_t OFF_X    = 0;              // 8192*256*2 = 4 MiB bf16 data
static constexpr size_t OFF_SQ   = 0x400000;       // 8192 f32 row sq-norms
static constexpr size_t OFF_XU   = 0x408000;       // 8192*32 bf16 padded weights
static constexpr size_t OFF_CP   = 0x488000;       // 64*256 f32 col partials
static constexpr size_t OFF_CLS  = 0x498000;       // 32*20 f32 class partials
static constexpr size_t OFF_PRES = 0x499000;       // 32 u32 presence partials
static constexpr size_t OFF_SC   = 0x49A000;       // 32 f32 scalars
static constexpr size_t OFF_PART = 0x49B000;       // 2080 f64 block partials

// scal: [0] = -1/(16*bw) (natural log), [5] = count_safe, [6..15] a_scale, [16..25] b_scale

__device__ __forceinline__ void gload_lds16(const void* g, void* l) {
    __builtin_amdgcn_global_load_lds((const __attribute__((address_space(1))) void*)g,
                                     (__attribute__((address_space(3))) void*)l, 16, 0, 0);
}

// ---------------------------------------------------------------------------
// 1) rows -> bf16 (RNE), per-row squared norm of the rounded data
// ---------------------------------------------------------------------------
__global__ void k_prep(const float* __restrict__ src, const float* __restrict__ tgt,
                       unsigned short* __restrict__ X, float* __restrict__ sq) {
    int wid  = threadIdx.x >> 6;
    int lane = threadIdx.x & 63;
    int row  = blockIdx.x * 4 + wid;
    const float* p = (row < BROWS) ? (src + (size_t)row * DDIM)
                                   : (tgt + (size_t)(row - BROWS) * DDIM);
    f32x4 v = *reinterpret_cast<const f32x4*>(p + lane * 4);
    unsigned short h[4];
    float ssum = 0.f;
#pragma unroll
    for (int e = 0; e < 4; ++e) {
        unsigned bits = __float_as_uint(v[e]);
        unsigned r = (bits + 0x7FFFu + ((bits >> 16) & 1u)) >> 16;   // RNE to bf16
        h[e] = (unsigned short)r;
        float f = __uint_as_float(r << 16);
        ssum += f * f;
    }
    ushort4 us; us.x = h[0]; us.y = h[1]; us.z = h[2]; us.w = h[3];
    *reinterpret_cast<ushort4*>(X + (size_t)row * DDIM + lane * 4) = us;
#pragma unroll
    for (int off = 32; off > 0; off >>= 1) ssum += __shfl_xor(ssum, off);
    if (lane == 0) sq[row] = ssum;
}

// ---------------------------------------------------------------------------
// 2) fused aux: blocks 0..63 = vectorized column sums; 64..95 = class sums
// ---------------------------------------------------------------------------
__global__ void k_aux(const unsigned short* __restrict__ X,
                      const float* __restrict__ label, const float* __restrict__ logits,
                      float* __restrict__ colpart, float* __restrict__ clspart,
                      unsigned* __restrict__ prespart) {
    __shared__ float shbuf[8][256];          // colsum path
    __shared__ float cbuf[256][NCLS];        // cls path
    __shared__ unsigned pm[128];
    int t = threadIdx.x;
    if (blockIdx.x < 64) {
        int b  = blockIdx.x;
        int cg = t & 31;        // 16B column chunk (8 dims)
        int rs = t >> 5;        // row sub-stripe 0..7
        const unsigned short* base = X + (size_t)(b * 128 + rs) * DDIM + cg * 8;
        float a[8];
#pragma unroll
        for (int e = 0; e < 8; ++e) a[e] = 0.f;
        for (int i = 0; i < 16; ++i) {
            u16x8 v = *reinterpret_cast<const u16x8*>(base + (size_t)i * 8 * DDIM);
#pragma unroll
            for (int e = 0; e < 8; ++e) a[e] += __uint_as_float((unsigned)v[e] << 16);
        }
#pragma unroll
        for (int e = 0; e < 8; ++e) shbuf[rs][cg * 8 + e] = a[e];
        __syncthreads();
        float s = 0.f;
#pragma unroll
        for (int k = 0; k < 8; ++k) s += shbuf[k][t];
        colpart[b * DDIM + t] = s;
    } else {
        int b = blockIdx.x - 64;
        int r = b * 128 + (t & 127);
        if (t < 128) {
            const float* lr = label + (size_t)r * NCLS;
#pragma unroll
            for (int c = 0; c < NCLS; ++c) cbuf[t][c] = lr[c];
        } else {
            const float* gr = logits + (size_t)r * NCLS;
            float bv = -1e30f; int bc = 0;
#pragma unroll
            for (int c = 0; c < NCLS; ++c) {
                float v = gr[c];
                cbuf[t][c] = v;
                if (v > bv) { bv = v; bc = c; }
            }
            pm[t - 128] = 1u << bc;
        }
        __syncthreads();
        if (t < NCLS) {
            float a = 0.f;
            for (int i = 0; i < 128; ++i) a += cbuf[i][t];
            clspart[b * 20 + t] = a;
        } else if (t < 2 * NCLS) {
            float a = 0.f;
            for (int i = 128; i < 256; ++i) a += cbuf[i][t - NCLS];
            clspart[b * 20 + t] = a;
        }
        if (t == 0) {
            unsigned p = 0;
            for (int i = 0; i < 128; ++i) p |= pm[i];
            prespart[b] = p;
        }
    }
}

// ---------------------------------------------------------------------------
// 3) stats: closed-form bandwidth, masks, scales (single small block)
// ---------------------------------------------------------------------------
__global__ void k_stats(const float* __restrict__ sq, const float* __restrict__ colpart,
                        const float* __restrict__ clspart, const unsigned* __restrict__ prespart,
                        float* __restrict__ scal) {
    __shared__ double dred[256];
    __shared__ float  cfin[2 * NCLS];
    __shared__ unsigned presAll;
    int t = threadIdx.x;

    double cd = 0.0;
    for (int b = 0; b < 64; ++b) cd += (double)colpart[b * DDIM + t];
    dred[t] = cd * cd;
    __syncthreads();
    for (int s = 128; s > 0; s >>= 1) { if (t < s) dred[t] += dred[t + s]; __syncthreads(); }
    double S_cs = dred[0];
    __syncthreads();

    double ss = 0.0;
    for (int k = 0; k < 32; ++k) ss += (double)sq[t + 256 * k];
    dred[t] = ss;
    __syncthreads();
    for (int s = 128; s > 0; s >>= 1) { if (t < s) dred[t] += dred[t + s]; __syncthreads(); }
    double S_sq = dred[0];
    __syncthreads();

    if (t < 2 * NCLS) {
        float a = 0.f;
        for (int b = 0; b < 32; ++b) a += clspart[b * 20 + t];
        cfin[t] = a;
    }
    if (t == 0) {
        unsigned p = 0;
        for (int b = 0; b < 32; ++b) p |= prespart[b];
        presAll = p;
    }
    __syncthreads();

    if (t == 0) {
        double nf = (double)N_TOTAL;
        double sum_l2 = 2.0 * nf * S_sq - 2.0 * S_cs;
        if (sum_l2 < 0.0) sum_l2 = 0.0;
        double bw = sum_l2 / (nf * nf - nf) / 4.0;
        scal[0] = (float)(-1.0 / (16.0 * bw));
        int count = 0;
        for (int c = 0; c < NCLS; ++c) {
            float sv = cfin[c], tv = cfin[NCLS + c];
            bool m = (sv > 0.f) && ((presAll >> c) & 1u);
            count += m ? 1 : 0;
            float sdiv = (sv == 0.f) ? 100.f : sv;
            float tdiv = (tv == 0.f) ? 100.f : tv;
            scal[6  + c] = m ? (1.f / sdiv) : 0.f;
            scal[16 + c] = m ? (1.f / tdiv) : 0.f;
        }
        scal[5] = (float)(count > 0 ? count : 1);
    }
}

// ---------------------------------------------------------------------------
// 4) build XU: 8192 x 32 bf16 padded weight rows
// ---------------------------------------------------------------------------
__global__ void k_build_xu(const float* __restrict__ label, const float* __restrict__ logits,
                           const float* __restrict__ scal, unsigned short* __restrict__ XU) {
    int r = blockIdx.x * blockDim.x + threadIdx.x;
    if (r >= N_TOTAL) return;
    float v[NCLS];
    if (r < BROWS) {
        const float* lr = label + (size_t)r * NCLS;
#pragma unroll
        for (int c = 0; c < NCLS; ++c) v[c] = lr[c] * scal[6 + c];
    } else {
        const float* gr = logits + (size_t)(r - BROWS) * NCLS;
#pragma unroll
        for (int c = 0; c < NCLS; ++c) v[c] = -gr[c] * scal[16 + c];
    }
    unsigned packed[16];
#pragma unroll
    for (int w = 0; w < 16; ++w) {
        unsigned lo = 0, hi = 0;
        if (2 * w < NCLS) {
            unsigned bits = __float_as_uint(v[2 * w]);
            lo = (bits + 0x7FFFu + ((bits >> 16) & 1u)) >> 16;
        }
        if (2 * w + 1 < NCLS) {
            unsigned bits = __float_as_uint(v[2 * w + 1]);
            hi = (bits + 0x7FFFu + ((bits >> 16) & 1u)) >> 16;
        }
        packed[w] = lo | (hi << 16);
    }
    uint4* out = reinterpret_cast<uint4*>(XU + (size_t)r * 32);
#pragma unroll
    for (int q = 0; q < 4; ++q)
        out[q] = make_uint4(packed[4*q], packed[4*q+1], packed[4*q+2], packed[4*q+3]);
}

// ---------------------------------------------------------------------------
// 5) main: LDS-staged 128x128 triangular tiles, 2-phase global_load_lds
//    pipeline, XOR-swizzled LDS (pre-swizzled source + swizzled ds_read)
// ---------------------------------------------------------------------------
__global__ __launch_bounds__(256, 4) void k_main(const unsigned short* __restrict__ X,
                                                 const unsigned short* __restrict__ XU,
                                                 const float* __restrict__ sq,
                                                 const float* __restrict__ scal,
                                                 double* __restrict__ partials) {
    // XCD-contiguous bid swizzle: XCD k gets original bids [k*260,(k+1)*260)
    int bid = (blockIdx.x & 7) * (NTRI / 8) + (blockIdx.x >> 3);
    int bi = 0, rem = bid;
    while (rem >= NB - bi) { rem -= NB - bi; ++bi; }
    int bj = bi + rem;

    int tid = threadIdx.x, lane = tid & 63, wid = tid >> 6;
    int wr = wid >> 1, wc = wid & 1;
    int lrow = lane & 15, kgrp = lane >> 4;

    __shared__ unsigned short Abuf[128 * 64];   // [row][64 k-shorts], 16B chunks XOR-swizzled
    __shared__ unsigned short Bbuf[128 * 64];
    __shared__ float red[4];
    char* AbufB = (char*)Abuf;
    char* BbufB = (char*)Bbuf;

    float nb = scal[0];

    f32x4 acc[4][4];
#pragma unroll
    for (int a = 0; a < 4; ++a)
#pragma unroll
        for (int b = 0; b < 4; ++b) acc[a][b] = (f32x4){0.f, 0.f, 0.f, 0.f};

    const size_t arow0 = (size_t)bi * 128;
    const size_t brow0 = (size_t)bj * 128;
    int qthr = wid * 64 + lane;   // this thread's chunk id base
    int ldsw = wid * 64;          // wave-uniform chunk base

    for (int ks = 0; ks < 4; ++ks) {
        // ---- stage A,B K-slice (async, pre-swizzled source, linear LDS dest)
#pragma unroll
        for (int it = 0; it < 4; ++it) {
            int q = it * 256 + qthr;              // chunk 0..1023
            int r = q >> 3, c = q & 7;
            int cs = c ^ (r & 7);                 // source column chunk (swizzle)
            size_t goff = (size_t)r * DDIM + ks * 64 + cs * 8;
            size_t loff = (size_t)(it * 256 + ldsw) * 16;
            gload_lds16(X + (arow0 * DDIM + goff), AbufB + loff);
            gload_lds16(X + (brow0 * DDIM + goff), BbufB + loff);
        }
        __syncthreads();   // vmcnt(0) drain + barrier

        // ---- compute: 2 k32 sub-steps
#pragma unroll
        for (int s = 0; s < 2; ++s) {
            int slot = ((s * 4 + kgrp) ^ (lrow & 7)) * 16;   // swizzled 16B slot in row
            bf16x8 af[4], bf[4];
#pragma unroll
            for (int f = 0; f < 4; ++f) {
                int ar = wr * 64 + f * 16 + lrow;
                af[f] = *reinterpret_cast<const bf16x8*>(AbufB + ar * 128 + slot);
                int br = wc * 64 + f * 16 + lrow;
                bf[f] = *reinterpret_cast<const bf16x8*>(BbufB + br * 128 + slot);
            }
#pragma unroll
            for (int a = 0; a < 4; ++a)
#pragma unroll
                for (int b = 0; b < 4; ++b)
                    acc[a][b] = __builtin_amdgcn_mfma_f32_16x16x32_bf16(af[a], bf[b], acc[a][b], 0, 0, 0);
        }
        __syncthreads();   // protect buffer for next stage
    }

    // ---- epilogue: MFMA weights + 1-exp kernel chain
    int i0 = bi * 128 + wr * 64;
    int j0 = bj * 128 + wc * 64;
    const unsigned short* AU = XU + (size_t)(i0 + lrow) * 32 + kgrp * 8;
    const unsigned short* BU = XU + (size_t)(j0 + lrow) * 32 + kgrp * 8;
    bf16x8 au[4];
#pragma unroll
    for (int f = 0; f < 4; ++f)
        au[f] = *reinterpret_cast<const bf16x8*>(AU + (size_t)f * 16 * 32);

    float lp = 0.f;
#pragma unroll
    for (int g = 0; g < 4; ++g) {
        bf16x8 bu = *reinterpret_cast<const bf16x8*>(BU + (size_t)g * 16 * 32);
        f32x4 wg[4];
#pragma unroll
        for (int f = 0; f < 4; ++f)
            wg[f] = __builtin_amdgcn_mfma_f32_16x16x32_bf16(au[f], bu, (f32x4){0.f,0.f,0.f,0.f}, 0, 0, 0);

        float sqj = sq[j0 + g * 16 + lrow];
#pragma unroll
        for (int f = 0; f < 4; ++f) {
            f32x4 sqi = *reinterpret_cast<const f32x4*>(sq + i0 + f * 16 + kgrp * 4);
#pragma unroll
            for (int r = 0; r < 4; ++r) {
                float l2 = fmaxf(sqi[r] + sqj - 2.f * acc[f][g][r], 0.f);
                float e1 = __expf(l2 * nb);
                float e2 = e1 * e1;
                float e4 = e2 * e2;
                float e8 = e4 * e4;
                float e16 = e8 * e8;
                float ksum = ((e1 + e2) + (e4 + e8)) + e16;
                lp = fmaf(wg[f][r], ksum, lp);
            }
        }
    }

    // ---- wave shuffle reduce + tiny LDS combine (1 barrier)
#pragma unroll
    for (int off = 32; off > 0; off >>= 1) lp += __shfl_xor(lp, off);
    if (lane == 0) red[wid] = lp;
    __syncthreads();
    if (tid == 0)
        partials[bid] = (double)((red[0] + red[1]) + (red[2] + red[3])) * ((bi == bj) ? 1.0 : 2.0);
}

// ---------------------------------------------------------------------------
// 6) final fixed-order reduction, divide by count
// ---------------------------------------------------------------------------
__global__ void k_final(const double* __restrict__ partials, const float* __restrict__ scal,
                        float* __restrict__ out) {
    __shared__ double dred[256];
    int t = threadIdx.x;
    double s = 0.0;
    for (int k = 0; k < 9; ++k) {
        int idx = t + 256 * k;
        if (idx < NTRI) s += partials[idx];
    }
    dred[t] = s;
    __syncthreads();
    for (int st = 128; st > 0; st >>= 1) { if (t < st) dred[t] += dred[t + st]; __syncthreads(); }
    if (t == 0) out[0] = (float)(dred[0] / (double)scal[5]);
}

extern "C" void kernel_launch(void* const* d_in, const int* in_sizes, int n_in,
                              void* d_out, int out_size, void* d_ws, size_t ws_size,
                              hipStream_t stream) {
    const float* src    = (const float*)d_in[0];
    const float* tgt    = (const float*)d_in[1];
    const float* label  = (const float*)d_in[2];
    const float* logits = (const float*)d_in[3];

    char* ws = (char*)d_ws;
    unsigned short* X   = (unsigned short*)(ws + OFF_X);
    float* sq           = (float*)(ws + OFF_SQ);
    unsigned short* XU  = (unsigned short*)(ws + OFF_XU);
    float* colpart      = (float*)(ws + OFF_CP);
    float* clspart      = (float*)(ws + OFF_CLS);
    unsigned* prespart  = (unsigned*)(ws + OFF_PRES);
    float* scal         = (float*)(ws + OFF_SC);
    double* partials    = (double*)(ws + OFF_PART);

    k_prep    <<<2048, 256, 0, stream>>>(src, tgt, X, sq);
    k_aux     <<<96,   256, 0, stream>>>(X, label, logits, colpart, clspart, prespart);
    k_stats   <<<1,    256, 0, stream>>>(sq, colpart, clspart, prespart, scal);
    k_build_xu<<<32,   256, 0, stream>>>(label, logits, scal, XU);
    k_main    <<<NTRI, 256, 0, stream>>>(X, XU, sq, scal, partials);
    k_final   <<<1,    256, 0, stream>>>(partials, scal, (float*)d_out);
}

// Round 4
// 56.564 us; speedup vs baseline: 2.9880x; 1.1487x over previous
//
#include <hip/hip_runtime.h>
#include <hip/hip_bf16.h>

#define N_TOTAL 8192
#define BROWS   4096
#define DDIM    256
#define NCLS    10
#define NB      64              // 128-row tiles per side
#define NTRI    (NB*(NB+1)/2)   // 2080 upper-tri blocks (= 8*260)
#define K_STEPS 8               // BK=32

typedef __attribute__((ext_vector_type(8))) short bf16x8;
typedef __attribute__((ext_vector_type(4))) float f32x4;
typedef __attribute__((ext_vector_type(2))) float f32x2;

// ---- workspace layout (bytes) ----
static constexpr size_t OFF_X    = 0;              // 8192*256*2 = 4 MiB bf16 data
static constexpr size_t OFF_SQ   = 0x400000;       // 8192 f32 row sq-norms
static constexpr size_t OFF_XU   = 0x408000;       // 8192*32 bf16 padded weights
static constexpr size_t OFF_CP   = 0x488000;       // 64*256 f32 col partials
static constexpr size_t OFF_CLS  = 0x498000;       // 32*20 f32 class partials
static constexpr size_t OFF_PRES = 0x499000;       // 32 u32 presence partials
static constexpr size_t OFF_SC   = 0x49A000;       // 32 f32 scalars
static constexpr size_t OFF_PART = 0x49B000;       // 2080 f64 block partials

// scal: [0] = -1/(16*bw) (natural log), [5] = count_safe

__device__ __forceinline__ void gload_lds16(const void* g, void* l) {
    __builtin_amdgcn_global_load_lds((const __attribute__((address_space(1))) void*)g,
                                     (__attribute__((address_space(3))) void*)l, 16, 0, 0);
}
__device__ __forceinline__ float rne_bf16_val(float x) {
    unsigned b = __float_as_uint(x);
    unsigned r = (b + 0x7FFFu + ((b >> 16) & 1u)) >> 16;
    return __uint_as_float(r << 16);
}

// ---------------------------------------------------------------------------
// 1) fused pre-pass:
//    blocks 0..2047    : rows -> bf16 X + row sq-norms
//    blocks 2048..2111 : column sums (recomputed from f32 src with same RNE)
//    blocks 2112..2143 : class sums + argmax presence
// ---------------------------------------------------------------------------
__global__ void k_pre(const float* __restrict__ src, const float* __restrict__ tgt,
                      const float* __restrict__ label, const float* __restrict__ logits,
                      unsigned short* __restrict__ X, float* __restrict__ sq,
                      float* __restrict__ colpart, float* __restrict__ clspart,
                      unsigned* __restrict__ prespart) {
    __shared__ float shbuf[8][256];
    __shared__ float cbuf[256][NCLS];
    __shared__ unsigned pm[128];
    int t = threadIdx.x;
    int bid = blockIdx.x;

    if (bid < 2048) {                 // ---- prep path
        int wid  = t >> 6;
        int lane = t & 63;
        int row  = bid * 4 + wid;
        const float* p = (row < BROWS) ? (src + (size_t)row * DDIM)
                                       : (tgt + (size_t)(row - BROWS) * DDIM);
        f32x4 v = *reinterpret_cast<const f32x4*>(p + lane * 4);
        unsigned short h[4];
        float ssum = 0.f;
#pragma unroll
        for (int e = 0; e < 4; ++e) {
            unsigned bits = __float_as_uint(v[e]);
            unsigned r = (bits + 0x7FFFu + ((bits >> 16) & 1u)) >> 16;
            h[e] = (unsigned short)r;
            float f = __uint_as_float(r << 16);
            ssum += f * f;
        }
        ushort4 us; us.x = h[0]; us.y = h[1]; us.z = h[2]; us.w = h[3];
        *reinterpret_cast<ushort4*>(X + (size_t)row * DDIM + lane * 4) = us;
#pragma unroll
        for (int off = 32; off > 0; off >>= 1) ssum += __shfl_xor(ssum, off);
        if (lane == 0) sq[row] = ssum;
    } else if (bid < 2112) {          // ---- colsum path (from f32 source, RNE inline)
        int b  = bid - 2048;          // 0..63 -> rows b*128..+127
        int cg = t & 31;              // 8-dim column chunk
        int rs = t >> 5;              // row sub-stripe 0..7
        const float* base = (b < 32)
            ? (src + ((size_t)(b * 128 + rs)) * DDIM + cg * 8)
            : (tgt + ((size_t)((b - 32) * 128 + rs)) * DDIM + cg * 8);
        float a[8];
#pragma unroll
        for (int e = 0; e < 8; ++e) a[e] = 0.f;
        for (int i = 0; i < 16; ++i) {
            const float* rp = base + (size_t)i * 8 * DDIM;
            f32x4 v0 = *reinterpret_cast<const f32x4*>(rp);
            f32x4 v1 = *reinterpret_cast<const f32x4*>(rp + 4);
#pragma unroll
            for (int e = 0; e < 4; ++e) a[e]     += rne_bf16_val(v0[e]);
#pragma unroll
            for (int e = 0; e < 4; ++e) a[4 + e] += rne_bf16_val(v1[e]);
        }
#pragma unroll
        for (int e = 0; e < 8; ++e) shbuf[rs][cg * 8 + e] = a[e];
        __syncthreads();
        float s = 0.f;
#pragma unroll
        for (int k = 0; k < 8; ++k) s += shbuf[k][t];
        colpart[b * DDIM + t] = s;
    } else {                          // ---- class-sum path
        int b = bid - 2112;           // 0..31
        int r = b * 128 + (t & 127);
        if (t < 128) {
            const float* lr = label + (size_t)r * NCLS;
#pragma unroll
            for (int c = 0; c < NCLS; ++c) cbuf[t][c] = lr[c];
        } else {
            const float* gr = logits + (size_t)r * NCLS;
            float bv = -1e30f; int bc = 0;
#pragma unroll
            for (int c = 0; c < NCLS; ++c) {
                float v = gr[c];
                cbuf[t][c] = v;
                if (v > bv) { bv = v; bc = c; }
            }
            pm[t - 128] = 1u << bc;
        }
        __syncthreads();
        if (t < NCLS) {
            float a = 0.f;
            for (int i = 0; i < 128; ++i) a += cbuf[i][t];
            clspart[b * 20 + t] = a;
        } else if (t < 2 * NCLS) {
            float a = 0.f;
            for (int i = 128; i < 256; ++i) a += cbuf[i][t - NCLS];
            clspart[b * 20 + t] = a;
        }
        if (t == 0) {
            unsigned p = 0;
            for (int i = 0; i < 128; ++i) p |= pm[i];
            prespart[b] = p;
        }
    }
}

// ---------------------------------------------------------------------------
// 2) scales + XU build fused (33 blocks): every block redundantly derives the
//    class scales; blocks 0..31 write XU rows; block 32 computes bandwidth.
// ---------------------------------------------------------------------------
__global__ void k_scales(const float* __restrict__ clspart, const unsigned* __restrict__ prespart,
                         const float* __restrict__ colpart, const float* __restrict__ sq,
                         const float* __restrict__ label, const float* __restrict__ logits,
                         float* __restrict__ scal, unsigned short* __restrict__ XU) {
    __shared__ float  cfin[2 * NCLS];
    __shared__ float  ascale[NCLS], bscale[NCLS];
    __shared__ unsigned presAll;
    __shared__ double dred[256];
    int t = threadIdx.x, b = blockIdx.x;

    if (t < 2 * NCLS) {
        float a = 0.f;
        for (int k = 0; k < 32; ++k) a += clspart[k * 20 + t];
        cfin[t] = a;
    }
    if (t == 0) {
        unsigned p = 0;
        for (int k = 0; k < 32; ++k) p |= prespart[k];
        presAll = p;
    }
    __syncthreads();
    if (t == 0) {
        int count = 0;
        for (int c = 0; c < NCLS; ++c) {
            float sv = cfin[c], tv = cfin[NCLS + c];
            bool m = (sv > 0.f) && ((presAll >> c) & 1u);
            count += m ? 1 : 0;
            float sdiv = (sv == 0.f) ? 100.f : sv;
            float tdiv = (tv == 0.f) ? 100.f : tv;
            ascale[c] = m ? (1.f / sdiv) : 0.f;
            bscale[c] = m ? (1.f / tdiv) : 0.f;
        }
        if (b == 32) scal[5] = (float)(count > 0 ? count : 1);
    }
    __syncthreads();

    if (b < 32) {                     // ---- XU rows
        int r = b * 256 + t;
        float v[NCLS];
        if (r < BROWS) {
            const float* lr = label + (size_t)r * NCLS;
#pragma unroll
            for (int c = 0; c < NCLS; ++c) v[c] = lr[c] * ascale[c];
        } else {
            const float* gr = logits + (size_t)(r - BROWS) * NCLS;
#pragma unroll
            for (int c = 0; c < NCLS; ++c) v[c] = -gr[c] * bscale[c];
        }
        unsigned packed[16];
#pragma unroll
        for (int w = 0; w < 16; ++w) {
            unsigned lo = 0, hi = 0;
            if (2 * w < NCLS) {
                unsigned bits = __float_as_uint(v[2 * w]);
                lo = (bits + 0x7FFFu + ((bits >> 16) & 1u)) >> 16;
            }
            if (2 * w + 1 < NCLS) {
                unsigned bits = __float_as_uint(v[2 * w + 1]);
                hi = (bits + 0x7FFFu + ((bits >> 16) & 1u)) >> 16;
            }
            packed[w] = lo | (hi << 16);
        }
        uint4* out = reinterpret_cast<uint4*>(XU + (size_t)r * 32);
#pragma unroll
        for (int q = 0; q < 4; ++q)
            out[q] = make_uint4(packed[4*q], packed[4*q+1], packed[4*q+2], packed[4*q+3]);
    } else {                          // ---- bandwidth (block 32)
        double cd = 0.0;
        for (int k = 0; k < 64; ++k) cd += (double)colpart[k * DDIM + t];
        dred[t] = cd * cd;
        __syncthreads();
        for (int s = 128; s > 0; s >>= 1) { if (t < s) dred[t] += dred[t + s]; __syncthreads(); }
        double S_cs = dred[0];
        __syncthreads();
        double ss = 0.0;
        for (int k = 0; k < 32; ++k) ss += (double)sq[t + 256 * k];
        dred[t] = ss;
        __syncthreads();
        for (int s = 128; s > 0; s >>= 1) { if (t < s) dred[t] += dred[t + s]; __syncthreads(); }
        if (t == 0) {
            double nf = (double)N_TOTAL;
            double sum_l2 = 2.0 * nf * dred[0] - 2.0 * S_cs;
            if (sum_l2 < 0.0) sum_l2 = 0.0;
            double bw = sum_l2 / (nf * nf - nf) / 4.0;
            scal[0] = (float)(-1.0 / (16.0 * bw));
        }
    }
}

// ---------------------------------------------------------------------------
// 3) main: BK=32 double-buffered 2-phase pipeline, bank-balanced linear LDS,
//    MFMA Gram + MFMA weights + packed 1-exp kernel chain
// ---------------------------------------------------------------------------
__global__ __launch_bounds__(256, 3) void k_main(const unsigned short* __restrict__ X,
                                                 const unsigned short* __restrict__ XU,
                                                 const float* __restrict__ sq,
                                                 const float* __restrict__ scal,
                                                 double* __restrict__ partials) {
    // XCD-contiguous bid swizzle (2080 = 8*260, bijective)
    int bid = (blockIdx.x & 7) * (NTRI / 8) + (blockIdx.x >> 3);
    int bi = 0, rem = bid;
    while (rem >= NB - bi) { rem -= NB - bi; ++bi; }
    int bj = bi + rem;

    int tid = threadIdx.x, lane = tid & 63, wid = tid >> 6;
    int wr = wid >> 1, wc = wid & 1;
    int lrow = lane & 15, kgrp = lane >> 4;

    __shared__ unsigned short Abuf[2 * 128 * 32];   // [buf][row][32 k-shorts]
    __shared__ unsigned short Bbuf[2 * 128 * 32];
    __shared__ float red[4];
    char* AB = (char*)Abuf;
    char* BB = (char*)Bbuf;

    float nb = scal[0];

    f32x4 acc[4][4];
#pragma unroll
    for (int a = 0; a < 4; ++a)
#pragma unroll
        for (int b = 0; b < 4; ++b) acc[a][b] = (f32x4){0.f, 0.f, 0.f, 0.f};

    // staging pointers: thread = chunk tid (row tid>>2, col-chunk tid&3), +64 rows
    const unsigned short* gA0 = X + ((size_t)bi * 128 + (tid >> 2)) * DDIM + (tid & 3) * 8;
    const unsigned short* gA1 = gA0 + (size_t)64 * DDIM;
    const unsigned short* gB0 = X + ((size_t)bj * 128 + (tid >> 2)) * DDIM + (tid & 3) * 8;
    const unsigned short* gB1 = gB0 + (size_t)64 * DDIM;
    int lds0 = tid * 16;                                  // linear LDS chunk
    int aoff = (wr * 64 + lrow) * 64 + kgrp * 16;         // ds_read base (bytes)
    int boff = (wc * 64 + lrow) * 64 + kgrp * 16;

#define STAGE(BS, KS) do { \
    gload_lds16(gA0 + (KS) * 32, AB + (BS) * 8192 + lds0); \
    gload_lds16(gA1 + (KS) * 32, AB + (BS) * 8192 + lds0 + 4096); \
    gload_lds16(gB0 + (KS) * 32, BB + (BS) * 8192 + lds0); \
    gload_lds16(gB1 + (KS) * 32, BB + (BS) * 8192 + lds0 + 4096); \
} while (0)

#define COMPUTE(BS) do { \
    bf16x8 af[4], bf[4]; \
    _Pragma("unroll") \
    for (int f = 0; f < 4; ++f) { \
        af[f] = *reinterpret_cast<const bf16x8*>(AB + (BS) * 8192 + aoff + f * 1024); \
        bf[f] = *reinterpret_cast<const bf16x8*>(BB + (BS) * 8192 + boff + f * 1024); \
    } \
    _Pragma("unroll") \
    for (int a = 0; a < 4; ++a) \
        _Pragma("unroll") \
        for (int b = 0; b < 4; ++b) \
            acc[a][b] = __builtin_amdgcn_mfma_f32_16x16x32_bf16(af[a], bf[b], acc[a][b], 0, 0, 0); \
} while (0)

    STAGE(0, 0);
    __syncthreads();
#pragma unroll
    for (int t = 0; t < K_STEPS - 1; ++t) {
        STAGE((t + 1) & 1, t + 1);     // issue next-slice loads first
        COMPUTE(t & 1);                // compute current slice
        __syncthreads();               // drain + protect
    }

    // ---- epilogue operand prefetch (overlaps with final compute)
    int i0 = bi * 128 + wr * 64;
    int j0 = bj * 128 + wc * 64;
    const unsigned short* AU = XU + (size_t)(i0 + lrow) * 32 + kgrp * 8;
    const unsigned short* BU = XU + (size_t)(j0 + lrow) * 32 + kgrp * 8;
    bf16x8 au[4], bu[4];
#pragma unroll
    for (int f = 0; f < 4; ++f) {
        au[f] = *reinterpret_cast<const bf16x8*>(AU + (size_t)f * 16 * 32);
        bu[f] = *reinterpret_cast<const bf16x8*>(BU + (size_t)f * 16 * 32);
    }
    f32x4 sqin[4];
#pragma unroll
    for (int f = 0; f < 4; ++f)
        sqin[f] = *reinterpret_cast<const f32x4*>(sq + i0 + f * 16 + kgrp * 4);
    float sqjn[4];
#pragma unroll
    for (int g = 0; g < 4; ++g) sqjn[g] = sq[j0 + g * 16 + lrow];

    COMPUTE((K_STEPS - 1) & 1);        // last K-slice

    // pre-scale by nb (natural-log exponent scale); clamp moves to fmin after scale
#pragma unroll
    for (int f = 0; f < 4; ++f) sqin[f] *= nb;
#pragma unroll
    for (int g = 0; g < 4; ++g) sqjn[g] *= nb;
    float m2nb = -2.f * nb;

    f32x2 lp2 = (f32x2){0.f, 0.f};
#pragma unroll
    for (int g = 0; g < 4; ++g) {
        f32x4 wf[4];
#pragma unroll
        for (int f = 0; f < 4; ++f)
            wf[f] = __builtin_amdgcn_mfma_f32_16x16x32_bf16(au[f], bu[g], (f32x4){0.f,0.f,0.f,0.f}, 0, 0, 0);
#pragma unroll
        for (int f = 0; f < 4; ++f) {
#pragma unroll
            for (int h = 0; h < 2; ++h) {
                f32x2 ssn = (f32x2){ sqin[f][2*h] + sqjn[g], sqin[f][2*h+1] + sqjn[g] };
                f32x2 tt  = (f32x2){ fmaf(acc[f][g][2*h],   m2nb, ssn.x),
                                     fmaf(acc[f][g][2*h+1], m2nb, ssn.y) };
                tt.x = fminf(tt.x, 0.f);
                tt.y = fminf(tt.y, 0.f);
                f32x2 e;
                e.x = __expf(tt.x);
                e.y = __expf(tt.y);
                f32x2 e2 = e * e, e4 = e2 * e2, e8 = e4 * e4, e16 = e8 * e8;
                f32x2 ks = ((e + e2) + (e4 + e8)) + e16;
                lp2.x = fmaf(wf[f][2*h],   ks.x, lp2.x);
                lp2.y = fmaf(wf[f][2*h+1], ks.y, lp2.y);
            }
        }
    }
    float lp = lp2.x + lp2.y;

#pragma unroll
    for (int off = 32; off > 0; off >>= 1) lp += __shfl_xor(lp, off);
    if (lane == 0) red[wid] = lp;
    __syncthreads();
    if (tid == 0)
        partials[bid] = (double)((red[0] + red[1]) + (red[2] + red[3])) * ((bi == bj) ? 1.0 : 2.0);
#undef STAGE
#undef COMPUTE
}

// ---------------------------------------------------------------------------
// 4) final fixed-order reduction, divide by count
// ---------------------------------------------------------------------------
__global__ void k_final(const double* __restrict__ partials, const float* __restrict__ scal,
                        float* __restrict__ out) {
    __shared__ double dred[256];
    int t = threadIdx.x;
    double s = 0.0;
    for (int k = 0; k < 9; ++k) {
        int idx = t + 256 * k;
        if (idx < NTRI) s += partials[idx];
    }
    dred[t] = s;
    __syncthreads();
    for (int st = 128; st > 0; st >>= 1) { if (t < st) dred[t] += dred[t + st]; __syncthreads(); }
    if (t == 0) out[0] = (float)(dred[0] / (double)scal[5]);
}

extern "C" void kernel_launch(void* const* d_in, const int* in_sizes, int n_in,
                              void* d_out, int out_size, void* d_ws, size_t ws_size,
                              hipStream_t stream) {
    const float* src    = (const float*)d_in[0];
    const float* tgt    = (const float*)d_in[1];
    const float* label  = (const float*)d_in[2];
    const float* logits = (const float*)d_in[3];

    char* ws = (char*)d_ws;
    unsigned short* X   = (unsigned short*)(ws + OFF_X);
    float* sq           = (float*)(ws + OFF_SQ);
    unsigned short* XU  = (unsigned short*)(ws + OFF_XU);
    float* colpart      = (float*)(ws + OFF_CP);
    float* clspart      = (float*)(ws + OFF_CLS);
    unsigned* prespart  = (unsigned*)(ws + OFF_PRES);
    float* scal         = (float*)(ws + OFF_SC);
    double* partials    = (double*)(ws + OFF_PART);

    k_pre    <<<2144, 256, 0, stream>>>(src, tgt, label, logits, X, sq, colpart, clspart, prespart);
    k_scales <<<33,   256, 0, stream>>>(clspart, prespart, colpart, sq, label, logits, scal, XU);
    k_main   <<<NTRI, 256, 0, stream>>>(X, XU, sq, scal, partials);
    k_final  <<<1,    256, 0, stream>>>(partials, scal, (float*)d_out);
}